// Round 9
// baseline (159.537 us; speedup 1.0000x reference)
//
#include <hip/hip_runtime.h>

#define B_ 256
#define K_ 10
#define I_ 1152
#define O_ 16
#define C_ 8
#define BKO (B_*K_*O_)   // 40960
#define NX 72            // i0 blocks (uhat grid.x)

static __device__ __forceinline__ unsigned short f32_bf16(float f) {
    unsigned int u = __float_as_uint(f);
    u += 0x7FFFu + ((u >> 16) & 1u);           // round-to-nearest-even
    return (unsigned short)(u >> 16);
}

// DPP butterfly add step (full-rate VALU; ctrl is a compile-time const)
template <int CTRL>
static __device__ __forceinline__ float dpp_add(float v) {
    int x = __builtin_amdgcn_update_dpp(0, __float_as_int(v), CTRL, 0xF, 0xF, true);
    return v + __int_as_float(x);
}
// sum over each 16-lane DPP row: xor1, xor2, half-mirror, mirror
static __device__ __forceinline__ float row16_sum(float v) {
    v = dpp_add<0xB1>(v);     // quad_perm(1,0,3,2)  : + lane^1
    v = dpp_add<0x4E>(v);     // quad_perm(2,3,0,1)  : + lane^2
    v = dpp_add<0x141>(v);    // row_half_mirror     : + other quad
    v = dpp_add<0x140>(v);    // row_mirror          : + other half-row
    return v;
}
// sum over the 4 lanes of each quad (the og group) — VALU-rate, no LDS pipe
static __device__ __forceinline__ float quad4_sum(float v) {
    v = dpp_add<0xB1>(v);     // + lane^1
    v = dpp_add<0x4E>(v);     // + lane^2
    return v;
}

// ---------------------------------------------------------------------------
// uhat_kernel v7 (FROZEN): u[b][k][i][o] = bf16(w·x) + pass-1 partials
// part[x][k][b][o].  grid (72, 4, 10); 256 thr; 4 b per thread.
// ---------------------------------------------------------------------------
__global__ __launch_bounds__(256) void uhat_kernel(
    const float* __restrict__ x, const float* __restrict__ w,
    unsigned short* __restrict__ u, float* __restrict__ part)
{
    __shared__ float w_lds[16 * 132];   // [ii][o*8+c], stride 132: 2-way max
    __shared__ float p_lds[64 * 17];    // [b_local*17 + o], padded rows
    const int t   = threadIdx.x;
    const int i_l = t & 15, tg = t >> 4;
    const int i0  = blockIdx.x * 16;
    const int b0  = blockIdx.y * 64 + tg * 4;
    const int k   = blockIdx.z;
    const int i   = i0 + i_l;
    const bool row_leader = (i_l == 0);

    float4 xr[4][2];
#pragma unroll
    for (int bb = 0; bb < 4; bb++) {
        const float4* xp = (const float4*)(x + ((size_t)(b0 + bb) * I_ + i) * C_);
        xr[bb][0] = xp[0];
        xr[bb][1] = xp[1];
    }

    {
        const float4* ws = (const float4*)(w + ((size_t)k * I_ + i0) * O_ * C_);
#pragma unroll
        for (int r = 0; r < 2; r++) {
            int idx = r * 256 + t;               // float4 index in 16x128 slab
            int ii = idx >> 5, rem = idx & 31;
            *(float4*)&w_lds[ii * 132 + rem * 4] = ws[idx];
        }
    }
    __syncthreads();

    unsigned int pk[4][8];
#pragma unroll
    for (int oo = 0; oo < 8; oo++) {             // o-pair index
        float d[4][2];
#pragma unroll
        for (int h = 0; h < 2; h++) {
            const int o = oo * 2 + h;
            const float4 w0 = *(const float4*)&w_lds[i_l * 132 + o * 8];
            const float4 w1 = *(const float4*)&w_lds[i_l * 132 + o * 8 + 4];
#pragma unroll
            for (int bb = 0; bb < 4; bb++) {
                d[bb][h] = w0.x*xr[bb][0].x + w0.y*xr[bb][0].y
                         + w0.z*xr[bb][0].z + w0.w*xr[bb][0].w
                         + w1.x*xr[bb][1].x + w1.y*xr[bb][1].y
                         + w1.z*xr[bb][1].z + w1.w*xr[bb][1].w;
            }
        }
        // pass-1 fold: i-sum via DPP rows (16 lanes = the 16 i's)
#pragma unroll
        for (int bb = 0; bb < 4; bb++) {
#pragma unroll
            for (int h = 0; h < 2; h++) {
                const float rs = row16_sum(d[bb][h]);
                if (row_leader)
                    p_lds[(tg * 4 + bb) * 17 + oo * 2 + h] = rs;
            }
        }
#pragma unroll
        for (int bb = 0; bb < 4; bb++)
            pk[bb][oo] = (unsigned int)f32_bf16(d[bb][0]) |
                         ((unsigned int)f32_bf16(d[bb][1]) << 16);
    }
    // fused 32 B u store per (b,k,i)
#pragma unroll
    for (int bb = 0; bb < 4; bb++) {
        unsigned int* dst = (unsigned int*)
            (u + (((size_t)(b0 + bb) * K_ + k) * I_ + i) * O_);
        *(uint4*)(dst)     = make_uint4(pk[bb][0], pk[bb][1], pk[bb][2], pk[bb][3]);
        *(uint4*)(dst + 4) = make_uint4(pk[bb][4], pk[bb][5], pk[bb][6], pk[bb][7]);
    }

    // dense partial store: part[x][k][b][o] — wave writes 1024 B contiguous
    __syncthreads();
    {
        const int bl = t >> 2, o4 = (t & 3) * 4;     // b_local, o-quad
        float4 v;
        v.x = p_lds[bl * 17 + o4 + 0];
        v.y = p_lds[bl * 17 + o4 + 1];
        v.z = p_lds[bl * 17 + o4 + 2];
        v.w = p_lds[bl * 17 + o4 + 3];
        *(float4*)&part[(((size_t)blockIdx.x * K_ + k) * 256
                         + blockIdx.y * 64 + bl) * O_ + o4] = v;
    }
}

// ---------------------------------------------------------------------------
// route_all v14: v8's og=4 per-element math at v13's 16-wave occupancy.
// v13 (og=8) cost 1.67x the logit VALU per element (2FMA+3DPP per 2 MACs
// vs 4FMA+2DPP per 4 MACs) and 2x the load instructions + exp/Z dup.
// v14: 1024 thr, og = t&3 (o-quad, uint2 8B loads), i_l = t>>2 in [0,256).
// Chunks of 256 i: 4 full + 1 half-tail (i_l<128; quads share i_l so DPP
// groups stay exec-uniform).  1-deep P/Q prefetch; live set ~105 VGPR.
// ---------------------------------------------------------------------------
static __device__ __forceinline__ void sweep(
    const char* __restrict__ ubb,   // byte ptr: u + b*K*I*O elements
    int i_l, int og, const float* __restrict__ v_lds, float acc[K_][4])
{
#pragma unroll
    for (int k = 0; k < K_; k++)
#pragma unroll
        for (int j = 0; j < 4; j++) acc[k][j] = 0.f;

    const int base = i_l * 32 + og * 8;   // bytes within a k-slab, chunk 0

    uint2 P[K_], Q[K_];
#pragma unroll
    for (int k = 0; k < K_; k++)
        P[k] = *(const uint2*)(ubb + k * 36864 + base);

#pragma unroll 1
    for (int ic = 0; ic < 5; ic++) {
        if (ic < 4) {
            const bool nxt_ok = (ic < 3) || (i_l < 128);   // chunk 4 is half
            if (nxt_ok) {
#pragma unroll
                for (int k = 0; k < K_; k++)
                    Q[k] = *(const uint2*)
                        (ubb + k * 36864 + (ic + 1) * 8192 + base);
            }
        }
        if ((ic < 4) || (i_l < 128)) {
            float c_[K_];
            float Z = 0.f;
#pragma unroll
            for (int k = 0; k < K_; k++) {
                const float f0 = __uint_as_float(P[k].x << 16);
                const float f1 = __uint_as_float(P[k].x & 0xffff0000u);
                const float f2 = __uint_as_float(P[k].y << 16);
                const float f3 = __uint_as_float(P[k].y & 0xffff0000u);
                const float4 vk = *(const float4*)&v_lds[k * 16 + og * 4];
                float lk = f0*vk.x + f1*vk.y + f2*vk.z + f3*vk.w;
                lk = quad4_sum(lk);           // o-sum across the 4 og lanes
                c_[k] = __expf(lk); Z += c_[k];
            }
            const float inv = 1.0f / Z;
#pragma unroll
            for (int k = 0; k < K_; k++) {
                const float ck = c_[k] * inv;
                acc[k][0] = fmaf(ck, __uint_as_float(P[k].x << 16),         acc[k][0]);
                acc[k][1] = fmaf(ck, __uint_as_float(P[k].x & 0xffff0000u), acc[k][1]);
                acc[k][2] = fmaf(ck, __uint_as_float(P[k].y << 16),         acc[k][2]);
                acc[k][3] = fmaf(ck, __uint_as_float(P[k].y & 0xffff0000u), acc[k][3]);
            }
        }
        if (ic < 4) {
#pragma unroll
            for (int k = 0; k < K_; k++) P[k] = Q[k];
        }
    }
}

// reduce acc over the 16 i-positions of each wave; deposit per-wave sums.
// red: [16 waves][160]
static __device__ __forceinline__ void block_reduce(
    float acc[K_][4], float* __restrict__ red, int lane, int wv)
{
#pragma unroll
    for (int k = 0; k < K_; k++)
#pragma unroll
        for (int j = 0; j < 4; j++) {
            float a = acc[k][j];
            a += __shfl_xor(a, 4);  a += __shfl_xor(a, 8);
            a += __shfl_xor(a, 16); a += __shfl_xor(a, 32);
            acc[k][j] = a;
        }
    if (lane < 4) {
#pragma unroll
        for (int k = 0; k < K_; k++)
            *(float4*)&red[wv * 160 + k * 16 + lane * 4] =
                make_float4(acc[k][0], acc[k][1], acc[k][2], acc[k][3]);
    }
    __syncthreads();
}

// sum the 16 per-wave partials for element t (t < 160)
static __device__ __forceinline__ float sum16(const float* __restrict__ red, int t)
{
    float s = 0.f;
#pragma unroll
    for (int wgi = 0; wgi < 16; wgi++) s += red[wgi * 160 + t];
    return s;
}

// squash for element t<160: 16-lane o-group norm reduce
static __device__ __forceinline__ float squash_v(float s) {
    float n2 = s * s;
    n2 += __shfl_xor(n2, 1); n2 += __shfl_xor(n2, 2);
    n2 += __shfl_xor(n2, 4); n2 += __shfl_xor(n2, 8);
    const float norm = sqrtf(n2);
    return s * (n2 / (1.0f + n2) / (norm + 1e-9f));
}

// ---------------------------------------------------------------------------
// route_all v14: passes 2+3; pass 1 from part[x][k][b][o].
// grid (256), 1024 thr (16 waves, 4/SIMD).
// ---------------------------------------------------------------------------
__global__ __launch_bounds__(1024) void route_all(
    const unsigned short* __restrict__ u, const float* __restrict__ part,
    float* __restrict__ out)
{
    __shared__ float red[16 * 160];
    __shared__ float v_lds[160];
    __shared__ float v1_lds[160];

    const int t    = threadIdx.x;
    const int og   = t & 3, i_l = t >> 2;   // og: o-quad, i_l in 0..255
    const int b    = blockIdx.x;
    const int lane = t & 63, wv = t >> 6;   // wv in 0..15

    const char* ubb = (const char*)(u + (size_t)b * K_ * I_ * O_);
    float acc[K_][4];

    // ---- prologue: s1 = sum over the 72 i-blocks; v1 = squash(s1/K) ----
    if (t < 160) {
        const int k = t >> 4, o = t & 15;
        const float* pb = part + ((size_t)k * 256 + b) * O_ + o;
        float s = 0.f;
#pragma unroll
        for (int xb = 0; xb < NX; xb++)
            s += pb[(size_t)xb * BKO];
        float v = squash_v(s * (1.0f / K_));
        v1_lds[t] = v;
        v_lds[t]  = v;
    }
    __syncthreads();

    // ---- pass 2: logits from v1 ----
    sweep(ubb, i_l, og, v_lds, acc);
    block_reduce(acc, red, lane, wv);
    float v12 = 0.f;
    if (t < 160) v12 = v1_lds[t] + squash_v(sum16(red, t));
    __syncthreads();          // all sum16 reads done before v_lds overwrite
    if (t < 160) v_lds[t] = v12;
    __syncthreads();

    // ---- pass 3: logits from v1+v2 (telescoped) ----
    sweep(ubb, i_l, og, v_lds, acc);
    block_reduce(acc, red, lane, wv);
    if (t < 160)
        out[(size_t)b * 160 + t] = squash_v(sum16(red, t));
}

// ---------------------------------------------------------------------------
extern "C" void kernel_launch(void* const* d_in, const int* in_sizes, int n_in,
                              void* d_out, int out_size, void* d_ws, size_t ws_size,
                              hipStream_t stream)
{
    const float* x = (const float*)d_in[0];
    const float* w = (const float*)d_in[1];
    float* outp = (float*)d_out;

    float* part = (float*)d_ws;                          // NX*BKO f32 = 11.8 MB
    unsigned short* u = (unsigned short*)(part + (size_t)NX * BKO);  // 94.4 MB

    uhat_kernel<<<dim3(72, 4, 10), 256, 0, stream>>>(x, w, u, part);
    route_all<<<B_, 1024, 0, stream>>>(u, part, outp);
}

// Round 10
// 125.617 us; speedup vs baseline: 1.2700x; 1.2700x over previous
//
#include <hip/hip_runtime.h>

#define B_ 256
#define K_ 10
#define I_ 1152
#define O_ 16
#define C_ 8
#define BKO (B_*K_*O_)   // 40960
#define NX 72            // i0 blocks (uhat grid.x)

static __device__ __forceinline__ unsigned short f32_bf16(float f) {
    unsigned int u = __float_as_uint(f);
    u += 0x7FFFu + ((u >> 16) & 1u);           // round-to-nearest-even
    return (unsigned short)(u >> 16);
}

// DPP butterfly add step (full-rate VALU; ctrl is a compile-time const)
template <int CTRL>
static __device__ __forceinline__ float dpp_add(float v) {
    int x = __builtin_amdgcn_update_dpp(0, __float_as_int(v), CTRL, 0xF, 0xF, true);
    return v + __int_as_float(x);
}
// sum over each 16-lane DPP row: xor1, xor2, half-mirror, mirror
static __device__ __forceinline__ float row16_sum(float v) {
    v = dpp_add<0xB1>(v);     // quad_perm(1,0,3,2)  : + lane^1
    v = dpp_add<0x4E>(v);     // quad_perm(2,3,0,1)  : + lane^2
    v = dpp_add<0x141>(v);    // row_half_mirror     : + other quad
    v = dpp_add<0x140>(v);    // row_mirror          : + other half-row
    return v;
}
// sum over 8 consecutive lanes (one i, og=0..7): quad sum + mirrored quad
static __device__ __forceinline__ float quad8_sum(float v) {
    v = dpp_add<0xB1>(v);     // + lane^1
    v = dpp_add<0x4E>(v);     // + lane^2
    v = dpp_add<0x141>(v);    // row_half_mirror: + other quad of the 8
    return v;
}

// ---------------------------------------------------------------------------
// uhat_kernel v8: k-PAIRED.  grid (72, 4, 5); each block computes k0=2z and
// k0+1 with x loaded ONCE (x re-read traffic 94 -> 47 MB).  w and p_lds are
// double-slabbed; both w slabs staged up front (one barrier).  Per-k math,
// stores, and rounding identical to v7 -> bit-identical output.
// LDS 25.6 KB -> 6 blocks/CU cap, grid 1440 = 5.6/CU co-resident.
// ---------------------------------------------------------------------------
__global__ __launch_bounds__(256) void uhat_kernel(
    const float* __restrict__ x, const float* __restrict__ w,
    unsigned short* __restrict__ u, float* __restrict__ part)
{
    __shared__ float w_lds[2][16 * 132];   // [kk][ii][o*8+c], stride 132
    __shared__ float p_lds[2][64 * 17];    // [kk][b_local*17 + o]
    const int t   = threadIdx.x;
    const int i_l = t & 15, tg = t >> 4;
    const int i0  = blockIdx.x * 16;
    const int b0  = blockIdx.y * 64 + tg * 4;
    const int k0  = blockIdx.z * 2;
    const int i   = i0 + i_l;
    const bool row_leader = (i_l == 0);

    float4 xr[4][2];
#pragma unroll
    for (int bb = 0; bb < 4; bb++) {
        const float4* xp = (const float4*)(x + ((size_t)(b0 + bb) * I_ + i) * C_);
        xr[bb][0] = xp[0];
        xr[bb][1] = xp[1];
    }

#pragma unroll
    for (int kk = 0; kk < 2; kk++) {
        const float4* ws = (const float4*)(w + ((size_t)(k0 + kk) * I_ + i0) * O_ * C_);
#pragma unroll
        for (int r = 0; r < 2; r++) {
            int idx = r * 256 + t;               // float4 index in 16x128 slab
            int ii = idx >> 5, rem = idx & 31;
            *(float4*)&w_lds[kk][ii * 132 + rem * 4] = ws[idx];
        }
    }
    __syncthreads();

#pragma unroll
    for (int kk = 0; kk < 2; kk++) {
        const int k = k0 + kk;
        unsigned int pk[4][8];
#pragma unroll
        for (int oo = 0; oo < 8; oo++) {             // o-pair index
            float d[4][2];
#pragma unroll
            for (int h = 0; h < 2; h++) {
                const int o = oo * 2 + h;
                const float4 w0 = *(const float4*)&w_lds[kk][i_l * 132 + o * 8];
                const float4 w1 = *(const float4*)&w_lds[kk][i_l * 132 + o * 8 + 4];
#pragma unroll
                for (int bb = 0; bb < 4; bb++) {
                    d[bb][h] = w0.x*xr[bb][0].x + w0.y*xr[bb][0].y
                             + w0.z*xr[bb][0].z + w0.w*xr[bb][0].w
                             + w1.x*xr[bb][1].x + w1.y*xr[bb][1].y
                             + w1.z*xr[bb][1].z + w1.w*xr[bb][1].w;
                }
            }
            // pass-1 fold: i-sum via DPP rows (16 lanes = the 16 i's)
#pragma unroll
            for (int bb = 0; bb < 4; bb++) {
#pragma unroll
                for (int h = 0; h < 2; h++) {
                    const float rs = row16_sum(d[bb][h]);
                    if (row_leader)
                        p_lds[kk][(tg * 4 + bb) * 17 + oo * 2 + h] = rs;
                }
            }
#pragma unroll
            for (int bb = 0; bb < 4; bb++)
                pk[bb][oo] = (unsigned int)f32_bf16(d[bb][0]) |
                             ((unsigned int)f32_bf16(d[bb][1]) << 16);
        }
        // fused 32 B u store per (b,k,i)
#pragma unroll
        for (int bb = 0; bb < 4; bb++) {
            unsigned int* dst = (unsigned int*)
                (u + (((size_t)(b0 + bb) * K_ + k) * I_ + i) * O_);
            *(uint4*)(dst)     = make_uint4(pk[bb][0], pk[bb][1], pk[bb][2], pk[bb][3]);
            *(uint4*)(dst + 4) = make_uint4(pk[bb][4], pk[bb][5], pk[bb][6], pk[bb][7]);
        }
    }

    // dense partial stores: part[x][k][b][o] — wave writes 1024 B contiguous
    __syncthreads();
    {
        const int bl = t >> 2, o4 = (t & 3) * 4;     // b_local, o-quad
#pragma unroll
        for (int kk = 0; kk < 2; kk++) {
            float4 v;
            v.x = p_lds[kk][bl * 17 + o4 + 0];
            v.y = p_lds[kk][bl * 17 + o4 + 1];
            v.z = p_lds[kk][bl * 17 + o4 + 2];
            v.w = p_lds[kk][bl * 17 + o4 + 3];
            *(float4*)&part[(((size_t)blockIdx.x * K_ + (k0 + kk)) * 256
                             + blockIdx.y * 64 + bl) * O_ + o4] = v;
        }
    }
}

// ---------------------------------------------------------------------------
// route_all v13 (REVERTED to round-8 measured best: route ~39.6 us).
// 1024 thr = 16 waves = 4/SIMD; og = t&7 (o-pair, dword loads), live set
// ~50 VGPR fits the 64-reg cap the allocator imposes on 1024-thr blocks
// (v14's og=4 needed ~85 -> spilled 104 MB).  Barrier-free register sweep.
// ---------------------------------------------------------------------------
static __device__ __forceinline__ void sweep(
    const char* __restrict__ ubb,   // byte ptr: u + b*K*I*O elements
    int i_l, int og, const float* __restrict__ v_lds, float acc[K_][2])
{
#pragma unroll
    for (int k = 0; k < K_; k++) { acc[k][0] = 0.f; acc[k][1] = 0.f; }

    const int base = i_l * 32 + og * 4;       // bytes within (k, chunk) slab

    unsigned int P[K_], Q[K_];
#pragma unroll
    for (int k = 0; k < K_; k++)
        P[k] = *(const unsigned int*)(ubb + k * 36864 + base);

#pragma unroll 1
    for (int ic = 0; ic < 9; ic++) {
        if (ic + 1 < 9) {
#pragma unroll
            for (int k = 0; k < K_; k++)
                Q[k] = *(const unsigned int*)
                    (ubb + k * 36864 + (ic + 1) * 4096 + base);
        }
        float c_[K_];
        float Z = 0.f;
#pragma unroll
        for (int k = 0; k < K_; k++) {
            const float f0 = __uint_as_float(P[k] << 16);
            const float f1 = __uint_as_float(P[k] & 0xffff0000u);
            const float2 vk = *(const float2*)&v_lds[k * 16 + og * 2];
            float lk = f0 * vk.x + f1 * vk.y;
            lk = quad8_sum(lk);               // o-sum across 8 og lanes
            c_[k] = __expf(lk); Z += c_[k];
        }
        const float inv = 1.0f / Z;
#pragma unroll
        for (int k = 0; k < K_; k++) {
            const float ck = c_[k] * inv;
            acc[k][0] = fmaf(ck, __uint_as_float(P[k] << 16),         acc[k][0]);
            acc[k][1] = fmaf(ck, __uint_as_float(P[k] & 0xffff0000u), acc[k][1]);
        }
#pragma unroll
        for (int k = 0; k < K_; k++) P[k] = Q[k];
    }
}

// reduce acc over the 8 i-positions of each wave; deposit per-wave sums.
// red: [16 waves][160]
static __device__ __forceinline__ void block_reduce(
    float acc[K_][2], float* __restrict__ red, int lane, int wv)
{
#pragma unroll
    for (int k = 0; k < K_; k++)
#pragma unroll
        for (int j = 0; j < 2; j++) {
            float a = acc[k][j];
            a += __shfl_xor(a, 8); a += __shfl_xor(a, 16); a += __shfl_xor(a, 32);
            acc[k][j] = a;
        }
    if (lane < 8) {
#pragma unroll
        for (int k = 0; k < K_; k++)
            *(float2*)&red[wv * 160 + k * 16 + lane * 2] =
                make_float2(acc[k][0], acc[k][1]);
    }
    __syncthreads();
}

// sum the 16 per-wave partials for element t (t < 160)
static __device__ __forceinline__ float sum16(const float* __restrict__ red, int t)
{
    float s = 0.f;
#pragma unroll
    for (int wgi = 0; wgi < 16; wgi++) s += red[wgi * 160 + t];
    return s;
}

// squash for element t<160: 16-lane o-group norm reduce
static __device__ __forceinline__ float squash_v(float s) {
    float n2 = s * s;
    n2 += __shfl_xor(n2, 1); n2 += __shfl_xor(n2, 2);
    n2 += __shfl_xor(n2, 4); n2 += __shfl_xor(n2, 8);
    const float norm = sqrtf(n2);
    return s * (n2 / (1.0f + n2) / (norm + 1e-9f));
}

// ---------------------------------------------------------------------------
// route_all v13: passes 2+3; pass 1 from part[x][k][b][o].
// grid (256), 1024 thr (16 waves, 4/SIMD).
// ---------------------------------------------------------------------------
__global__ __launch_bounds__(1024) void route_all(
    const unsigned short* __restrict__ u, const float* __restrict__ part,
    float* __restrict__ out)
{
    __shared__ float red[16 * 160];
    __shared__ float v_lds[160];
    __shared__ float v1_lds[160];

    const int t    = threadIdx.x;
    const int og   = t & 7, i_l = t >> 3;   // og: o-pair idx, i_l in 0..127
    const int b    = blockIdx.x;
    const int lane = t & 63, wv = t >> 6;   // wv in 0..15

    const char* ubb = (const char*)(u + (size_t)b * K_ * I_ * O_);
    float acc[K_][2];

    // ---- prologue: s1 = sum over the 72 i-blocks; v1 = squash(s1/K) ----
    if (t < 160) {
        const int k = t >> 4, o = t & 15;
        const float* pb = part + ((size_t)k * 256 + b) * O_ + o;
        float s = 0.f;
#pragma unroll
        for (int xb = 0; xb < NX; xb++)
            s += pb[(size_t)xb * BKO];
        float v = squash_v(s * (1.0f / K_));
        v1_lds[t] = v;
        v_lds[t]  = v;
    }
    __syncthreads();

    // ---- pass 2: logits from v1 ----
    sweep(ubb, i_l, og, v_lds, acc);
    block_reduce(acc, red, lane, wv);
    float v12 = 0.f;
    if (t < 160) v12 = v1_lds[t] + squash_v(sum16(red, t));
    __syncthreads();          // all sum16 reads done before v_lds overwrite
    if (t < 160) v_lds[t] = v12;
    __syncthreads();

    // ---- pass 3: logits from v1+v2 (telescoped) ----
    sweep(ubb, i_l, og, v_lds, acc);
    block_reduce(acc, red, lane, wv);
    if (t < 160)
        out[(size_t)b * 160 + t] = squash_v(sum16(red, t));
}

// ---------------------------------------------------------------------------
extern "C" void kernel_launch(void* const* d_in, const int* in_sizes, int n_in,
                              void* d_out, int out_size, void* d_ws, size_t ws_size,
                              hipStream_t stream)
{
    const float* x = (const float*)d_in[0];
    const float* w = (const float*)d_in[1];
    float* outp = (float*)d_out;

    float* part = (float*)d_ws;                          // NX*BKO f32 = 11.8 MB
    unsigned short* u = (unsigned short*)(part + (size_t)NX * BKO);  // 94.4 MB

    uhat_kernel<<<dim3(72, 4, 5), 256, 0, stream>>>(x, w, u, part);
    route_all<<<B_, 1024, 0, stream>>>(u, part, outp);
}

// Round 11
// 120.966 us; speedup vs baseline: 1.3189x; 1.0384x over previous
//
#include <hip/hip_runtime.h>

#define B_ 256
#define K_ 10
#define I_ 1152
#define O_ 16
#define C_ 8
#define BKO (B_*K_*O_)   // 40960
#define NX 72            // i0 blocks (uhat grid.x)

static __device__ __forceinline__ unsigned short f32_bf16(float f) {
    unsigned int u = __float_as_uint(f);
    u += 0x7FFFu + ((u >> 16) & 1u);           // round-to-nearest-even
    return (unsigned short)(u >> 16);
}

// DPP butterfly add step (full-rate VALU; ctrl is a compile-time const)
template <int CTRL>
static __device__ __forceinline__ float dpp_add(float v) {
    int x = __builtin_amdgcn_update_dpp(0, __float_as_int(v), CTRL, 0xF, 0xF, true);
    return v + __int_as_float(x);
}
// sum over each 16-lane DPP row: xor1, xor2, half-mirror, mirror
static __device__ __forceinline__ float row16_sum(float v) {
    v = dpp_add<0xB1>(v);     // quad_perm(1,0,3,2)  : + lane^1
    v = dpp_add<0x4E>(v);     // quad_perm(2,3,0,1)  : + lane^2
    v = dpp_add<0x141>(v);    // row_half_mirror     : + other quad
    v = dpp_add<0x140>(v);    // row_mirror          : + other half-row
    return v;
}
// sum over 8 consecutive lanes (one i, og=0..7): quad sum + mirrored quad
static __device__ __forceinline__ float quad8_sum(float v) {
    v = dpp_add<0xB1>(v);     // + lane^1
    v = dpp_add<0x4E>(v);     // + lane^2
    v = dpp_add<0x141>(v);    // row_half_mirror: + other quad of the 8
    return v;
}

// ---------------------------------------------------------------------------
// uhat_kernel v7 (REVERTED to round-8 measured best; k-pairing was net
// negative: occupancy 32->24 waves/CU cost more than the x-traffic saved).
// u[b][k][i][o] = bf16(w·x) + pass-1 partials part[x][k][b][o].
// grid (72, 4, 10); 256 thr; 4 b per thread.
// ---------------------------------------------------------------------------
__global__ __launch_bounds__(256) void uhat_kernel(
    const float* __restrict__ x, const float* __restrict__ w,
    unsigned short* __restrict__ u, float* __restrict__ part)
{
    __shared__ float w_lds[16 * 132];   // [ii][o*8+c], stride 132: 2-way max
    __shared__ float p_lds[64 * 17];    // [b_local*17 + o], padded rows
    const int t   = threadIdx.x;
    const int i_l = t & 15, tg = t >> 4;
    const int i0  = blockIdx.x * 16;
    const int b0  = blockIdx.y * 64 + tg * 4;
    const int k   = blockIdx.z;
    const int i   = i0 + i_l;
    const bool row_leader = (i_l == 0);

    float4 xr[4][2];
#pragma unroll
    for (int bb = 0; bb < 4; bb++) {
        const float4* xp = (const float4*)(x + ((size_t)(b0 + bb) * I_ + i) * C_);
        xr[bb][0] = xp[0];
        xr[bb][1] = xp[1];
    }

    {
        const float4* ws = (const float4*)(w + ((size_t)k * I_ + i0) * O_ * C_);
#pragma unroll
        for (int r = 0; r < 2; r++) {
            int idx = r * 256 + t;               // float4 index in 16x128 slab
            int ii = idx >> 5, rem = idx & 31;
            *(float4*)&w_lds[ii * 132 + rem * 4] = ws[idx];
        }
    }
    __syncthreads();

    unsigned int pk[4][8];
#pragma unroll
    for (int oo = 0; oo < 8; oo++) {             // o-pair index
        float d[4][2];
#pragma unroll
        for (int h = 0; h < 2; h++) {
            const int o = oo * 2 + h;
            const float4 w0 = *(const float4*)&w_lds[i_l * 132 + o * 8];
            const float4 w1 = *(const float4*)&w_lds[i_l * 132 + o * 8 + 4];
#pragma unroll
            for (int bb = 0; bb < 4; bb++) {
                d[bb][h] = w0.x*xr[bb][0].x + w0.y*xr[bb][0].y
                         + w0.z*xr[bb][0].z + w0.w*xr[bb][0].w
                         + w1.x*xr[bb][1].x + w1.y*xr[bb][1].y
                         + w1.z*xr[bb][1].z + w1.w*xr[bb][1].w;
            }
        }
        // pass-1 fold: i-sum via DPP rows (16 lanes = the 16 i's)
#pragma unroll
        for (int bb = 0; bb < 4; bb++) {
#pragma unroll
            for (int h = 0; h < 2; h++) {
                const float rs = row16_sum(d[bb][h]);
                if (row_leader)
                    p_lds[(tg * 4 + bb) * 17 + oo * 2 + h] = rs;
            }
        }
#pragma unroll
        for (int bb = 0; bb < 4; bb++)
            pk[bb][oo] = (unsigned int)f32_bf16(d[bb][0]) |
                         ((unsigned int)f32_bf16(d[bb][1]) << 16);
    }
    // fused 32 B u store per (b,k,i)
#pragma unroll
    for (int bb = 0; bb < 4; bb++) {
        unsigned int* dst = (unsigned int*)
            (u + (((size_t)(b0 + bb) * K_ + k) * I_ + i) * O_);
        *(uint4*)(dst)     = make_uint4(pk[bb][0], pk[bb][1], pk[bb][2], pk[bb][3]);
        *(uint4*)(dst + 4) = make_uint4(pk[bb][4], pk[bb][5], pk[bb][6], pk[bb][7]);
    }

    // dense partial store: part[x][k][b][o] — wave writes 1024 B contiguous
    __syncthreads();
    {
        const int bl = t >> 2, o4 = (t & 3) * 4;     // b_local, o-quad
        float4 v;
        v.x = p_lds[bl * 17 + o4 + 0];
        v.y = p_lds[bl * 17 + o4 + 1];
        v.z = p_lds[bl * 17 + o4 + 2];
        v.w = p_lds[bl * 17 + o4 + 3];
        *(float4*)&part[(((size_t)blockIdx.x * K_ + k) * 256
                         + blockIdx.y * 64 + bl) * O_ + o4] = v;
    }
}

// ---------------------------------------------------------------------------
// route_all v15 = v13 + pass-3 LDS persistence.  Evidence: FETCH=104 MB =
// exactly one u read from HBM -> pass-2 misses L3 (write-no-allocate),
// pass-3 hits L3/L2.  v13 used 11.5 KB of LDS at 1 block/CU; 148 KB idle.
// During pass-2's sweep we ALSO stage chunks 0-2 (120 KB) into LDS via
// global_load_lds (same cache lines the register path fetches -> ~no extra
// traffic; completion guaranteed by block_reduce's __syncthreads vmcnt
// drain).  Pass-3 serves chunks 0-2 from LDS, 3-8 via the v13 register
// path.  Chunk order and per-chunk math unchanged -> bit-identical.
// ---------------------------------------------------------------------------

// stage one 40 KB chunk with 1024 threads: 2560 x 16 B units, 2.5 rounds.
// r=2 is a half round: waves 0-7 only (wave-uniform guard).
static __device__ __forceinline__ void stage_chunk_1024(
    const char* __restrict__ ubb, int chunk, int t, char* lds_buf)
{
    const size_t coff = (size_t)chunk * 4096;
#pragma unroll
    for (int r = 0; r < 3; r++) {
        if (r < 2 || t < 512) {
            const int L   = r * 1024 + t;     // 16B-unit index in [0,2560)
            const int k   = L >> 8, rem = L & 255;
            const char* src = ubb + (size_t)k * 36864 + coff + (size_t)rem * 16;
            char* dst = lds_buf + ((size_t)(r * 1024 + (t & ~63)) * 16);
            __builtin_amdgcn_global_load_lds(
                (const __attribute__((address_space(1))) unsigned int*)src,
                (__attribute__((address_space(3))) unsigned int*)dst,
                16, 0, 0);
        }
    }
}

// one chunk's softmax+accumulate given the 10 per-k dwords in PP[]
#define CHUNK_OG8(PP) do {                                                    \
    float c_[K_]; float Z = 0.f;                                              \
    _Pragma("unroll")                                                         \
    for (int k = 0; k < K_; k++) {                                            \
        const float f0 = __uint_as_float(PP[k] << 16);                        \
        const float f1 = __uint_as_float(PP[k] & 0xffff0000u);                \
        const float2 vk = *(const float2*)&v_lds[k * 16 + og * 2];            \
        float lk = f0 * vk.x + f1 * vk.y;                                     \
        lk = quad8_sum(lk);                                                   \
        c_[k] = __expf(lk); Z += c_[k];                                       \
    }                                                                         \
    const float inv = 1.0f / Z;                                               \
    _Pragma("unroll")                                                         \
    for (int k = 0; k < K_; k++) {                                            \
        const float ck = c_[k] * inv;                                         \
        acc[k][0] = fmaf(ck, __uint_as_float(PP[k] << 16),         acc[k][0]);\
        acc[k][1] = fmaf(ck, __uint_as_float(PP[k] & 0xffff0000u), acc[k][1]);\
    }                                                                         \
} while (0)

// pass-2 sweep: v13 register path over all 9 chunks; additionally issues
// the LDS stages for chunks 0-2 (retired by the next __syncthreads).
static __device__ __forceinline__ void sweep_pass2(
    const char* __restrict__ ubb, int t, int i_l, int og,
    const float* __restrict__ v_lds, float acc[K_][2], char* __restrict__ ubuf)
{
#pragma unroll
    for (int k = 0; k < K_; k++) { acc[k][0] = 0.f; acc[k][1] = 0.f; }

    stage_chunk_1024(ubb, 0, t, ubuf);
    stage_chunk_1024(ubb, 1, t, ubuf + 40960);
    stage_chunk_1024(ubb, 2, t, ubuf + 81920);

    const int base = i_l * 32 + og * 4;       // bytes within (k, chunk) slab

    unsigned int P[K_], Q[K_];
#pragma unroll
    for (int k = 0; k < K_; k++)
        P[k] = *(const unsigned int*)(ubb + k * 36864 + base);

#pragma unroll 1
    for (int ic = 0; ic < 9; ic++) {
        if (ic + 1 < 9) {
#pragma unroll
            for (int k = 0; k < K_; k++)
                Q[k] = *(const unsigned int*)
                    (ubb + k * 36864 + (ic + 1) * 4096 + base);
        }
        CHUNK_OG8(P);
#pragma unroll
        for (int k = 0; k < K_; k++) P[k] = Q[k];
    }
}

// pass-3 sweep: chunks 0-2 from LDS, 3-8 via register prefetch.
static __device__ __forceinline__ void sweep_pass3(
    const char* __restrict__ ubb, int i_l, int og,
    const float* __restrict__ v_lds, float acc[K_][2],
    const char* __restrict__ ubuf)
{
#pragma unroll
    for (int k = 0; k < K_; k++) { acc[k][0] = 0.f; acc[k][1] = 0.f; }

    const int base = i_l * 32 + og * 4;

    // chunks 0-2: LDS-resident (bit-identical bytes, same order)
#pragma unroll 1
    for (int ic = 0; ic < 3; ic++) {
        const char* cb = ubuf + (size_t)ic * 40960;
        unsigned int P[K_];
#pragma unroll
        for (int k = 0; k < K_; k++)
            P[k] = *(const unsigned int*)(cb + k * 4096 + base);
        CHUNK_OG8(P);
    }
    // chunks 3-8: register path
    unsigned int P[K_], Q[K_];
#pragma unroll
    for (int k = 0; k < K_; k++)
        P[k] = *(const unsigned int*)(ubb + k * 36864 + 3 * 4096 + base);
#pragma unroll 1
    for (int ic = 3; ic < 9; ic++) {
        if (ic + 1 < 9) {
#pragma unroll
            for (int k = 0; k < K_; k++)
                Q[k] = *(const unsigned int*)
                    (ubb + k * 36864 + (ic + 1) * 4096 + base);
        }
        CHUNK_OG8(P);
#pragma unroll
        for (int k = 0; k < K_; k++) P[k] = Q[k];
    }
}

// reduce acc over the 8 i-positions of each wave; deposit per-wave sums.
// red: [16 waves][160]
static __device__ __forceinline__ void block_reduce(
    float acc[K_][2], float* __restrict__ red, int lane, int wv)
{
#pragma unroll
    for (int k = 0; k < K_; k++)
#pragma unroll
        for (int j = 0; j < 2; j++) {
            float a = acc[k][j];
            a += __shfl_xor(a, 8); a += __shfl_xor(a, 16); a += __shfl_xor(a, 32);
            acc[k][j] = a;
        }
    if (lane < 8) {
#pragma unroll
        for (int k = 0; k < K_; k++)
            *(float2*)&red[wv * 160 + k * 16 + lane * 2] =
                make_float2(acc[k][0], acc[k][1]);
    }
    __syncthreads();
}

// sum the 16 per-wave partials for element t (t < 160)
static __device__ __forceinline__ float sum16(const float* __restrict__ red, int t)
{
    float s = 0.f;
#pragma unroll
    for (int wgi = 0; wgi < 16; wgi++) s += red[wgi * 160 + t];
    return s;
}

// squash for element t<160: 16-lane o-group norm reduce
static __device__ __forceinline__ float squash_v(float s) {
    float n2 = s * s;
    n2 += __shfl_xor(n2, 1); n2 += __shfl_xor(n2, 2);
    n2 += __shfl_xor(n2, 4); n2 += __shfl_xor(n2, 8);
    const float norm = sqrtf(n2);
    return s * (n2 / (1.0f + n2) / (norm + 1e-9f));
}

// ---------------------------------------------------------------------------
// route_all v15: passes 2+3; pass 1 from part[x][k][b][o].
// grid (256), 1024 thr (16 waves, 4/SIMD).  LDS 131.6 KB (3 chunks + red).
// ---------------------------------------------------------------------------
__global__ __launch_bounds__(1024) void route_all(
    const unsigned short* __restrict__ u, const float* __restrict__ part,
    float* __restrict__ out)
{
    __shared__ __align__(16) char ubuf[3 * 40960];
    __shared__ float red[16 * 160];
    __shared__ float v_lds[160];
    __shared__ float v1_lds[160];

    const int t    = threadIdx.x;
    const int og   = t & 7, i_l = t >> 3;   // og: o-pair idx, i_l in 0..127
    const int b    = blockIdx.x;
    const int lane = t & 63, wv = t >> 6;   // wv in 0..15

    const char* ubb = (const char*)(u + (size_t)b * K_ * I_ * O_);
    float acc[K_][2];

    // ---- prologue: s1 = sum over the 72 i-blocks; v1 = squash(s1/K) ----
    if (t < 160) {
        const int k = t >> 4, o = t & 15;
        const float* pb = part + ((size_t)k * 256 + b) * O_ + o;
        float s = 0.f;
#pragma unroll
        for (int xb = 0; xb < NX; xb++)
            s += pb[(size_t)xb * BKO];
        float v = squash_v(s * (1.0f / K_));
        v1_lds[t] = v;
        v_lds[t]  = v;
    }
    __syncthreads();

    // ---- pass 2: logits from v1 (also stages chunks 0-2 into LDS) ----
    sweep_pass2(ubb, t, i_l, og, v_lds, acc, ubuf);
    block_reduce(acc, red, lane, wv);   // __syncthreads drains the stages
    float v12 = 0.f;
    if (t < 160) v12 = v1_lds[t] + squash_v(sum16(red, t));
    __syncthreads();          // all sum16 reads done before v_lds overwrite
    if (t < 160) v_lds[t] = v12;
    __syncthreads();

    // ---- pass 3: logits from v1+v2 (telescoped); chunks 0-2 from LDS ----
    sweep_pass3(ubb, i_l, og, v_lds, acc, ubuf);
    block_reduce(acc, red, lane, wv);
    if (t < 160)
        out[(size_t)b * 160 + t] = squash_v(sum16(red, t));
}

// ---------------------------------------------------------------------------
extern "C" void kernel_launch(void* const* d_in, const int* in_sizes, int n_in,
                              void* d_out, int out_size, void* d_ws, size_t ws_size,
                              hipStream_t stream)
{
    const float* x = (const float*)d_in[0];
    const float* w = (const float*)d_in[1];
    float* outp = (float*)d_out;

    float* part = (float*)d_ws;                          // NX*BKO f32 = 11.8 MB
    unsigned short* u = (unsigned short*)(part + (size_t)NX * BKO);  // 94.4 MB

    uhat_kernel<<<dim3(72, 4, 10), 256, 0, stream>>>(x, w, u, part);
    route_all<<<B_, 1024, 0, stream>>>(u, part, outp);
}

// Round 12
// 120.487 us; speedup vs baseline: 1.3241x; 1.0040x over previous
//
#include <hip/hip_runtime.h>

#define B_ 256
#define K_ 10
#define I_ 1152
#define O_ 16
#define C_ 8
#define BKO (B_*K_*O_)   // 40960
#define NX 72            // i0 blocks (uhat grid.x)
// u layout (v16, chunk-major): u[b][ic][k][i127][o], ic in [0,9), i127 in [0,128)
// per-b slice = 9*10*128*16 shorts = 368640 B; chunk (b,ic) = 40960 B contiguous.

static __device__ __forceinline__ unsigned short f32_bf16(float f) {
    unsigned int u = __float_as_uint(f);
    u += 0x7FFFu + ((u >> 16) & 1u);           // round-to-nearest-even
    return (unsigned short)(u >> 16);
}

// DPP butterfly add step (full-rate VALU; ctrl is a compile-time const)
template <int CTRL>
static __device__ __forceinline__ float dpp_add(float v) {
    int x = __builtin_amdgcn_update_dpp(0, __float_as_int(v), CTRL, 0xF, 0xF, true);
    return v + __int_as_float(x);
}
// sum over each 16-lane DPP row: xor1, xor2, half-mirror, mirror
static __device__ __forceinline__ float row16_sum(float v) {
    v = dpp_add<0xB1>(v);     // quad_perm(1,0,3,2)  : + lane^1
    v = dpp_add<0x4E>(v);     // quad_perm(2,3,0,1)  : + lane^2
    v = dpp_add<0x141>(v);    // row_half_mirror     : + other quad
    v = dpp_add<0x140>(v);    // row_mirror          : + other half-row
    return v;
}
// sum over 8 consecutive lanes (one i, og=0..7): quad sum + mirrored quad
static __device__ __forceinline__ float quad8_sum(float v) {
    v = dpp_add<0xB1>(v);     // + lane^1
    v = dpp_add<0x4E>(v);     // + lane^2
    v = dpp_add<0x141>(v);    // row_half_mirror: + other quad of the 8
    return v;
}

// ---------------------------------------------------------------------------
// uhat_kernel v9 = v7 + chunk-major u store.  Only the u-store offsets
// change: i = bx*16+i_l -> ic = bx>>3, i127 = (bx&7)*16+i_l.  Lanes 0-15
// still write 512 B contiguous per (b, store) -> same write quality.
// grid (72, 4, 10); 256 thr; 4 b per thread.
// ---------------------------------------------------------------------------
__global__ __launch_bounds__(256) void uhat_kernel(
    const float* __restrict__ x, const float* __restrict__ w,
    unsigned short* __restrict__ u, float* __restrict__ part)
{
    __shared__ float w_lds[16 * 132];   // [ii][o*8+c], stride 132: 2-way max
    __shared__ float p_lds[64 * 17];    // [b_local*17 + o], padded rows
    const int t   = threadIdx.x;
    const int i_l = t & 15, tg = t >> 4;
    const int i0  = blockIdx.x * 16;
    const int b0  = blockIdx.y * 64 + tg * 4;
    const int k   = blockIdx.z;
    const int i   = i0 + i_l;
    const int ic   = blockIdx.x >> 3;              // chunk index
    const int i127 = ((blockIdx.x & 7) << 4) + i_l; // in-chunk i
    const bool row_leader = (i_l == 0);

    float4 xr[4][2];
#pragma unroll
    for (int bb = 0; bb < 4; bb++) {
        const float4* xp = (const float4*)(x + ((size_t)(b0 + bb) * I_ + i) * C_);
        xr[bb][0] = xp[0];
        xr[bb][1] = xp[1];
    }

    {
        const float4* ws = (const float4*)(w + ((size_t)k * I_ + i0) * O_ * C_);
#pragma unroll
        for (int r = 0; r < 2; r++) {
            int idx = r * 256 + t;               // float4 index in 16x128 slab
            int ii = idx >> 5, rem = idx & 31;
            *(float4*)&w_lds[ii * 132 + rem * 4] = ws[idx];
        }
    }
    __syncthreads();

    unsigned int pk[4][8];
#pragma unroll
    for (int oo = 0; oo < 8; oo++) {             // o-pair index
        float d[4][2];
#pragma unroll
        for (int h = 0; h < 2; h++) {
            const int o = oo * 2 + h;
            const float4 w0 = *(const float4*)&w_lds[i_l * 132 + o * 8];
            const float4 w1 = *(const float4*)&w_lds[i_l * 132 + o * 8 + 4];
#pragma unroll
            for (int bb = 0; bb < 4; bb++) {
                d[bb][h] = w0.x*xr[bb][0].x + w0.y*xr[bb][0].y
                         + w0.z*xr[bb][0].z + w0.w*xr[bb][0].w
                         + w1.x*xr[bb][1].x + w1.y*xr[bb][1].y
                         + w1.z*xr[bb][1].z + w1.w*xr[bb][1].w;
            }
        }
        // pass-1 fold: i-sum via DPP rows (16 lanes = the 16 i's)
#pragma unroll
        for (int bb = 0; bb < 4; bb++) {
#pragma unroll
            for (int h = 0; h < 2; h++) {
                const float rs = row16_sum(d[bb][h]);
                if (row_leader)
                    p_lds[(tg * 4 + bb) * 17 + oo * 2 + h] = rs;
            }
        }
#pragma unroll
        for (int bb = 0; bb < 4; bb++)
            pk[bb][oo] = (unsigned int)f32_bf16(d[bb][0]) |
                         ((unsigned int)f32_bf16(d[bb][1]) << 16);
    }
    // fused 32 B u store per (b,k,i): chunk-major layout
#pragma unroll
    for (int bb = 0; bb < 4; bb++) {
        unsigned int* dst = (unsigned int*)
            (u + ((((size_t)(b0 + bb) * 9 + ic) * K_ + k) * 128 + i127) * O_);
        *(uint4*)(dst)     = make_uint4(pk[bb][0], pk[bb][1], pk[bb][2], pk[bb][3]);
        *(uint4*)(dst + 4) = make_uint4(pk[bb][4], pk[bb][5], pk[bb][6], pk[bb][7]);
    }

    // dense partial store: part[x][k][b][o] — wave writes 1024 B contiguous
    __syncthreads();
    {
        const int bl = t >> 2, o4 = (t & 3) * 4;     // b_local, o-quad
        float4 v;
        v.x = p_lds[bl * 17 + o4 + 0];
        v.y = p_lds[bl * 17 + o4 + 1];
        v.z = p_lds[bl * 17 + o4 + 2];
        v.w = p_lds[bl * 17 + o4 + 3];
        *(float4*)&part[(((size_t)blockIdx.x * K_ + k) * 256
                         + blockIdx.y * 64 + bl) * O_ + o4] = v;
    }
}

// ---------------------------------------------------------------------------
// route_all v16 = v15 + chunk-major u.  Pass-2 read of chunk ic is now ONE
// CONTIGUOUS 40 KB window (was 10 scattered 4 KB windows 36.9 KB apart ->
// 256 B-granule requests, ~3 TB/s).  16 waves cover the window densely =
// sequential HBM streaming.  LDS staging (chunks 0-2 for pass-3) is linear.
// Element mapping per thread and all math unchanged -> bit-identical.
// ---------------------------------------------------------------------------

// stage one contiguous 40 KB chunk with 1024 threads: 2560 x 16 B units.
static __device__ __forceinline__ void stage_chunk_1024(
    const char* __restrict__ chunk_base, int t, char* lds_buf)
{
#pragma unroll
    for (int r = 0; r < 3; r++) {
        if (r < 2 || t < 512) {
            const int L = r * 1024 + t;       // 16B-unit index in [0,2560)
            const char* src = chunk_base + (size_t)L * 16;
            char* dst = lds_buf + ((size_t)(r * 1024 + (t & ~63)) * 16);
            __builtin_amdgcn_global_load_lds(
                (const __attribute__((address_space(1))) unsigned int*)src,
                (__attribute__((address_space(3))) unsigned int*)dst,
                16, 0, 0);
        }
    }
}

// one chunk's softmax+accumulate given the 10 per-k dwords in PP[]
#define CHUNK_OG8(PP) do {                                                    \
    float c_[K_]; float Z = 0.f;                                              \
    _Pragma("unroll")                                                         \
    for (int k = 0; k < K_; k++) {                                            \
        const float f0 = __uint_as_float(PP[k] << 16);                        \
        const float f1 = __uint_as_float(PP[k] & 0xffff0000u);                \
        const float2 vk = *(const float2*)&v_lds[k * 16 + og * 2];            \
        float lk = f0 * vk.x + f1 * vk.y;                                     \
        lk = quad8_sum(lk);                                                   \
        c_[k] = __expf(lk); Z += c_[k];                                       \
    }                                                                         \
    const float inv = 1.0f / Z;                                               \
    _Pragma("unroll")                                                         \
    for (int k = 0; k < K_; k++) {                                            \
        const float ck = c_[k] * inv;                                         \
        acc[k][0] = fmaf(ck, __uint_as_float(PP[k] << 16),         acc[k][0]);\
        acc[k][1] = fmaf(ck, __uint_as_float(PP[k] & 0xffff0000u), acc[k][1]);\
    }                                                                         \
} while (0)

// pass-2 sweep: register path over all 9 chunks (contiguous windows);
// also issues the LDS stages for chunks 0-2 (retired by next __syncthreads).
static __device__ __forceinline__ void sweep_pass2(
    const char* __restrict__ ubb, int t, int i_l, int og,
    const float* __restrict__ v_lds, float acc[K_][2], char* __restrict__ ubuf)
{
#pragma unroll
    for (int k = 0; k < K_; k++) { acc[k][0] = 0.f; acc[k][1] = 0.f; }

    stage_chunk_1024(ubb,          t, ubuf);
    stage_chunk_1024(ubb + 40960,  t, ubuf + 40960);
    stage_chunk_1024(ubb + 81920,  t, ubuf + 81920);

    const int base = i_l * 32 + og * 4;       // bytes within a (chunk,k) slab

    unsigned int P[K_], Q[K_];
#pragma unroll
    for (int k = 0; k < K_; k++)
        P[k] = *(const unsigned int*)(ubb + k * 4096 + base);

#pragma unroll 1
    for (int ic = 0; ic < 9; ic++) {
        if (ic + 1 < 9) {
            const char* nb = ubb + (size_t)(ic + 1) * 40960;
#pragma unroll
            for (int k = 0; k < K_; k++)
                Q[k] = *(const unsigned int*)(nb + k * 4096 + base);
        }
        CHUNK_OG8(P);
#pragma unroll
        for (int k = 0; k < K_; k++) P[k] = Q[k];
    }
}

// pass-3 sweep: chunks 0-2 from LDS, 3-8 via register prefetch.
static __device__ __forceinline__ void sweep_pass3(
    const char* __restrict__ ubb, int i_l, int og,
    const float* __restrict__ v_lds, float acc[K_][2],
    const char* __restrict__ ubuf)
{
#pragma unroll
    for (int k = 0; k < K_; k++) { acc[k][0] = 0.f; acc[k][1] = 0.f; }

    const int base = i_l * 32 + og * 4;

    // chunks 0-2: LDS-resident (bit-identical bytes, same order)
#pragma unroll 1
    for (int ic = 0; ic < 3; ic++) {
        const char* cb = ubuf + (size_t)ic * 40960;
        unsigned int P[K_];
#pragma unroll
        for (int k = 0; k < K_; k++)
            P[k] = *(const unsigned int*)(cb + k * 4096 + base);
        CHUNK_OG8(P);
    }
    // chunks 3-8: register path
    unsigned int P[K_], Q[K_];
#pragma unroll
    for (int k = 0; k < K_; k++)
        P[k] = *(const unsigned int*)(ubb + 3 * 40960 + k * 4096 + base);
#pragma unroll 1
    for (int ic = 3; ic < 9; ic++) {
        if (ic + 1 < 9) {
            const char* nb = ubb + (size_t)(ic + 1) * 40960;
#pragma unroll
            for (int k = 0; k < K_; k++)
                Q[k] = *(const unsigned int*)(nb + k * 4096 + base);
        }
        CHUNK_OG8(P);
#pragma unroll
        for (int k = 0; k < K_; k++) P[k] = Q[k];
    }
}

// reduce acc over the 8 i-positions of each wave; deposit per-wave sums.
// red: [16 waves][160]
static __device__ __forceinline__ void block_reduce(
    float acc[K_][2], float* __restrict__ red, int lane, int wv)
{
#pragma unroll
    for (int k = 0; k < K_; k++)
#pragma unroll
        for (int j = 0; j < 2; j++) {
            float a = acc[k][j];
            a += __shfl_xor(a, 8); a += __shfl_xor(a, 16); a += __shfl_xor(a, 32);
            acc[k][j] = a;
        }
    if (lane < 8) {
#pragma unroll
        for (int k = 0; k < K_; k++)
            *(float2*)&red[wv * 160 + k * 16 + lane * 2] =
                make_float2(acc[k][0], acc[k][1]);
    }
    __syncthreads();
}

// sum the 16 per-wave partials for element t (t < 160)
static __device__ __forceinline__ float sum16(const float* __restrict__ red, int t)
{
    float s = 0.f;
#pragma unroll
    for (int wgi = 0; wgi < 16; wgi++) s += red[wgi * 160 + t];
    return s;
}

// squash for element t<160: 16-lane o-group norm reduce
static __device__ __forceinline__ float squash_v(float s) {
    float n2 = s * s;
    n2 += __shfl_xor(n2, 1); n2 += __shfl_xor(n2, 2);
    n2 += __shfl_xor(n2, 4); n2 += __shfl_xor(n2, 8);
    const float norm = sqrtf(n2);
    return s * (n2 / (1.0f + n2) / (norm + 1e-9f));
}

// ---------------------------------------------------------------------------
// route_all v16: passes 2+3; pass 1 from part[x][k][b][o].
// grid (256), 1024 thr (16 waves, 4/SIMD).  LDS 131.6 KB (3 chunks + red).
// ---------------------------------------------------------------------------
__global__ __launch_bounds__(1024) void route_all(
    const unsigned short* __restrict__ u, const float* __restrict__ part,
    float* __restrict__ out)
{
    __shared__ __align__(16) char ubuf[3 * 40960];
    __shared__ float red[16 * 160];
    __shared__ float v_lds[160];
    __shared__ float v1_lds[160];

    const int t    = threadIdx.x;
    const int og   = t & 7, i_l = t >> 3;   // og: o-pair idx, i_l in 0..127
    const int b    = blockIdx.x;
    const int lane = t & 63, wv = t >> 6;   // wv in 0..15

    const char* ubb = (const char*)u + (size_t)b * 368640;
    float acc[K_][2];

    // ---- prologue: s1 = sum over the 72 i-blocks; v1 = squash(s1/K) ----
    if (t < 160) {
        const int k = t >> 4, o = t & 15;
        const float* pb = part + ((size_t)k * 256 + b) * O_ + o;
        float s = 0.f;
#pragma unroll
        for (int xb = 0; xb < NX; xb++)
            s += pb[(size_t)xb * BKO];
        float v = squash_v(s * (1.0f / K_));
        v1_lds[t] = v;
        v_lds[t]  = v;
    }
    __syncthreads();

    // ---- pass 2: logits from v1 (also stages chunks 0-2 into LDS) ----
    sweep_pass2(ubb, t, i_l, og, v_lds, acc, ubuf);
    block_reduce(acc, red, lane, wv);   // __syncthreads drains the stages
    float v12 = 0.f;
    if (t < 160) v12 = v1_lds[t] + squash_v(sum16(red, t));
    __syncthreads();          // all sum16 reads done before v_lds overwrite
    if (t < 160) v_lds[t] = v12;
    __syncthreads();

    // ---- pass 3: logits from v1+v2 (telescoped); chunks 0-2 from LDS ----
    sweep_pass3(ubb, i_l, og, v_lds, acc, ubuf);
    block_reduce(acc, red, lane, wv);
    if (t < 160)
        out[(size_t)b * 160 + t] = squash_v(sum16(red, t));
}

// ---------------------------------------------------------------------------
extern "C" void kernel_launch(void* const* d_in, const int* in_sizes, int n_in,
                              void* d_out, int out_size, void* d_ws, size_t ws_size,
                              hipStream_t stream)
{
    const float* x = (const float*)d_in[0];
    const float* w = (const float*)d_in[1];
    float* outp = (float*)d_out;

    float* part = (float*)d_ws;                          // NX*BKO f32 = 11.8 MB
    unsigned short* u = (unsigned short*)(part + (size_t)NX * BKO);  // 94.4 MB

    uhat_kernel<<<dim3(72, 4, 10), 256, 0, stream>>>(x, w, u, part);
    route_all<<<B_, 1024, 0, stream>>>(u, part, outp);
}